// Round 5
// baseline (452.894 us; speedup 1.0000x reference)
//
#include <hip/hip_runtime.h>
#include <hip/hip_bf16.h>
#include <hip/hip_cooperative_groups.h>
#include <cstdint>

namespace cg = cooperative_groups;

#define GAMMA 0.001f
// K padded 784 -> 896 = 7*128. Swizzled fp8 tile layout per 128-row tile
// (R8/R9-proven): addr = tile*114688 + kk*16384 + h*8192 + row*64
//                        + (q ^ ((row>>1)&3))*16
// where source byte k = kk*128 + q*32 + h*16 + [0..15].
#define TILE_BYTES 114688

typedef __attribute__((ext_vector_type(4))) float f32x4;
typedef __attribute__((ext_vector_type(8))) int v8i;
typedef __attribute__((ext_vector_type(8))) short bh8;  // 8 bf16
typedef unsigned char u8;

__device__ inline unsigned pack4_fp8(float4 f) {
  unsigned p = __builtin_amdgcn_cvt_pk_fp8_f32(f.x, f.y, 0, false);
  p = __builtin_amdgcn_cvt_pk_fp8_f32(f.z, f.w, p, true);
  return p;
}

__device__ inline ushort bf16u(float v) {
  __hip_bfloat16 h = __float2bfloat16(v);
  return *(ushort*)&h;
}

// ---------------------------------------------------------------------------
// R18: FUSED cooperative kernel. R0-R4 evidence: gemm K-loop is near its
// structural L2 roofline (~53us; 918MB L2 reads @17.3TB/s; 3 different
// K-loop structures all tie) but total(159.7) - gemm(53) - reduce(~4) -
// conv(<53, arithmetic says ~5-10) leaves ~90-100us of inter-launch/gap
// overhead. Fuse conv+prep -> gemm -> reduce into ONE dispatch with
// grid.sync() between phases. Phase bodies are byte-identical to the
// R4-proven kernels, wrapped in gridDim-agnostic work loops. Grid =
// per_cu*256 (occupancy-queried, clamped [256,1024]); multiples of 64
// preserve the chunk->XCD L2 mapping (gbx and gbx+1024 share the SAME
// chunk -> B-tile L2/L1 reuse within a block).
// launch_bounds(256,4): proven for both conv (R0) and gemm (R4, VGPR=64,
// no spill). LDS: conv 36.5KB (sred for reduce aliased onto xp) -> 4/CU.
// SPILL TRIPWIRE: WRITE_SIZE ~20MB expected; >>that means spill.
// ---------------------------------------------------------------------------
__global__ __launch_bounds__(256, 4) void fused_kernel(
    const float* __restrict__ x, const float* __restrict__ w1,
    const float* __restrict__ b1, const float* __restrict__ w2,
    const float* __restrict__ b2, const float* __restrict__ support,
    const float* __restrict__ alpha, u8* __restrict__ feats_t,
    u8* __restrict__ sup_t, float* __restrict__ beta, float* __restrict__ ef,
    float* __restrict__ partial, float* __restrict__ out) {
  __shared__ alignas(16) float xp[2][900];     // 30x30 zero-padded input
  __shared__ alignas(16) ushort a1h[2][2048];  // HWC bf16: (row*16+col)*8+ic
  __shared__ float w1s[72], b1s[8], b2s[16];
  __shared__ float w2s[1152];                  // raw w2 [oc][ic][9]
  __shared__ alignas(8) ushort sc[2][16][212]; // conv2 out bf16 [oc][pos]
  __shared__ alignas(16) u8 fb[2][784];
  __shared__ float red[256];

  int tid = threadIdx.x;
  int lane = tid & 63, wave = tid >> 6;

  // ===================== Phase A1: conv pairs (old bx 0..2047) ============
  for (int cbx = blockIdx.x; cbx < 2048; cbx += gridDim.x) {
    __syncthreads();  // LDS reuse across iterations

    for (int t = tid; t < 1800; t += 256) ((float*)xp)[t] = 0.f;
    for (int t = tid; t < 1024; t += 256)
      ((uint4*)a1h)[t] = (uint4){0, 0, 0, 0};
    if (tid < 72) w1s[tid] = w1[tid];
    if (tid < 8) b1s[tid] = b1[tid];
    if (tid < 16) b2s[tid] = b2[tid];
    for (int t = tid; t < 1152; t += 256) w2s[t] = w2[t];
    __syncthreads();

    // per-lane B-frags (weights): oc=lane&15, k=(tap=g*4+quad, ic=j)
    int oc = lane & 15, quad = lane >> 4;
    bh8 wf[3];
#pragma unroll
    for (int g = 0; g < 3; g++) {
      int tap = g * 4 + quad;
#pragma unroll
      for (int j = 0; j < 8; j++) {
        float v = (tap < 9) ? w2s[oc * 72 + j * 9 + tap] : 0.f;
        wf[g][j] = (short)bf16u(v);
      }
    }

    for (int t = tid; t < 392; t += 256) {
      int img = t >= 196, j = t - img * 196;
      float4 v = ((const float4*)(x + (size_t)(cbx * 2 + img) * 784))[j];
      int r = j / 7, c = (j % 7) * 4;
      float* p = &xp[img][(r + 1) * 30 + (c + 1)];
      p[0] = v.x; p[1] = v.y; p[2] = v.z; p[3] = v.w;
    }
    __syncthreads();

    // stage 1: conv1+bias+relu+maxpool2 -> a1h (HWC bf16) interiors
    for (int idx = tid; idx < 3136; idx += 256) {
      int img = idx >= 1568;
      int rem = idx - img * 1568;
      int c = rem / 196, r2 = rem % 196;
      int ph = r2 / 14, pw = r2 % 14;
      const float* w = &w1s[c * 9];
      const float* xb = &xp[img][(2 * ph) * 30 + (2 * pw)];
      float t[4][4];
#pragma unroll
      for (int a = 0; a < 4; a++) {
        float2 u0 = *(const float2*)(xb + a * 30);
        float2 u1 = *(const float2*)(xb + a * 30 + 2);
        t[a][0] = u0.x; t[a][1] = u0.y; t[a][2] = u1.x; t[a][3] = u1.y;
      }
      float s00 = 0, s01 = 0, s10 = 0, s11 = 0;
#pragma unroll
      for (int dy = 0; dy < 3; dy++)
#pragma unroll
        for (int dx = 0; dx < 3; dx++) {
          float wv = w[dy * 3 + dx];
          s00 += t[dy][dx] * wv;     s01 += t[dy][dx + 1] * wv;
          s10 += t[dy + 1][dx] * wv; s11 += t[dy + 1][dx + 1] * wv;
        }
      float mx = fmaxf(fmaxf(s00, s01), fmaxf(s10, s11));
      float val = fmaxf(mx + b1s[c], 0.f);
      a1h[img][((ph + 1) * 16 + (pw + 1)) * 8 + c] = bf16u(val);
    }
    __syncthreads();

    // stage 2 (MFMA): waves 0,1 -> img0; waves 2,3 -> img1.
    {
      int img2 = wave >> 1, half = wave & 1;
      int Tstart = half * 7, Tcnt = half ? 6 : 7;
      const ushort* abase = a1h[img2];
      int mrow = lane & 15;
      for (int t = 0; t < Tcnt; ++t) {
        int T = Tstart + t;
        int p = T * 16 + mrow;
        int pc = p > 195 ? 195 : p;
        int y = pc / 14, xq = pc - y * 14;
        int cell = y * 16 + xq;
        f32x4 acc = (f32x4){0, 0, 0, 0};
#pragma unroll
        for (int g = 0; g < 3; g++) {
          int tap = g * 4 + quad;
          const ushort* ap;
          if (g == 2 && quad > 0) {
            ap = abase;  // border cell (0,0): guaranteed zeros
          } else {
            int dy = tap / 3, dx = tap - dy * 3;
            ap = abase + (cell + dy * 16 + dx) * 8;
          }
          bh8 af = *(const bh8*)ap;
          acc =
              __builtin_amdgcn_mfma_f32_16x16x32_bf16(af, wf[g], acc, 0, 0, 0);
        }
        int pos0 = T * 16 + quad * 4;
        ushort4 s4;
        s4.x = bf16u(acc.x); s4.y = bf16u(acc.y);
        s4.z = bf16u(acc.z); s4.w = bf16u(acc.w);
        *(ushort4*)(&sc[img2][oc][pos0]) = s4;
      }
    }
    __syncthreads();

    // pooling + bias + relu + fp8 + fsq from sc
    int img = tid >> 7, r = tid & 127;
    float fsq = 0.f;
    if (r < 112) {
      int o = r & 15, y7 = r >> 4;
      const ushort* srow = sc[img][o];
      float bo = b2s[o];
#pragma unroll
      for (int x7 = 0; x7 < 7; x7++) {
        int p = 28 * y7 + 2 * x7;
        unsigned u0 = *(const unsigned*)(&srow[p]);
        unsigned u1 = *(const unsigned*)(&srow[p + 14]);
        float a = __uint_as_float(u0 << 16);
        float b = __uint_as_float(u0 & 0xffff0000u);
        float c = __uint_as_float(u1 << 16);
        float d = __uint_as_float(u1 & 0xffff0000u);
        float mx = fmaxf(fmaxf(a, b), fmaxf(c, d));
        float val = fmaxf(mx + bo, 0.f);
        fb[img][o * 49 + y7 * 7 + x7] =
            (u8)(__builtin_amdgcn_cvt_pk_fp8_f32(val, 0.f, 0, false) & 0xff);
        fsq += val * val;
      }
    }
    red[tid] = fsq;
    __syncthreads();
    for (int s = 64; s > 0; s >>= 1) {
      if ((tid & 127) < s) red[tid] += red[tid + s];
      __syncthreads();
    }
    if ((tid & 127) == 0) ef[cbx * 2 + img] = __expf(-GAMMA * red[tid]);

    // store feats: 2 imgs x 56 16B-units into swizzled tile layout
    if (tid < 112) {
      int im = tid >= 56, j = tid - im * 56;
      uint4 v;
      if (j < 49) v = ((const uint4*)fb[im])[j];
      else { v.x = 0; v.y = 0; v.z = 0; v.w = 0; }
      int n = cbx * 2 + im;
      int nt = n >> 7, nr = n & 127;
      int kk = j >> 3, u = j & 7, q = u >> 1, h = u & 1;
      int qs = q ^ ((nr >> 1) & 3);
      *(uint4*)(feats_t + (size_t)nt * TILE_BYTES + kk * 16384 + h * 8192 +
                nr * 64 + qs * 16) = v;
    }
  }

  // ===================== Phase A2: support prep (8192 rows) ===============
  for (int sb = blockIdx.x; sb < 2048; sb += gridDim.x) {
    int m = sb * 4 + wave;
    const float* row = support + (size_t)m * 784;
    int mt = m >> 7, mr = m & 127;
    u8* tb = sup_t + (size_t)mt * TILE_BYTES;
    float ss = 0.f;
    if (lane < 56) {  // 16B unit j covers source bytes 16j..16j+15
      uint4 w;
      if (lane < 49) {
        float4 f0 = ((const float4*)row)[lane * 4 + 0];
        float4 f1 = ((const float4*)row)[lane * 4 + 1];
        float4 f2 = ((const float4*)row)[lane * 4 + 2];
        float4 f3 = ((const float4*)row)[lane * 4 + 3];
        ss = f0.x * f0.x + f0.y * f0.y + f0.z * f0.z + f0.w * f0.w +
             f1.x * f1.x + f1.y * f1.y + f1.z * f1.z + f1.w * f1.w +
             f2.x * f2.x + f2.y * f2.y + f2.z * f2.z + f2.w * f2.w +
             f3.x * f3.x + f3.y * f3.y + f3.z * f3.z + f3.w * f3.w;
        w.x = pack4_fp8(f0); w.y = pack4_fp8(f1);
        w.z = pack4_fp8(f2); w.w = pack4_fp8(f3);
      } else {
        w.x = 0; w.y = 0; w.z = 0; w.w = 0;
      }
      int kk = lane >> 3, u = lane & 7, q = u >> 1, h = u & 1;
      int qs = q ^ ((mr >> 1) & 3);
      *(uint4*)(tb + kk * 16384 + h * 8192 + mr * 64 + qs * 16) = w;
    }
#pragma unroll
    for (int s = 1; s < 64; s <<= 1) ss += __shfl_xor(ss, s, 64);
    if (lane == 0) {
      float es = __expf(-GAMMA * ss);
      float4 a = ((const float4*)alpha)[m];
      float4 b;
      b.x = es * a.x; b.y = es * a.y; b.z = es * a.z; b.w = es * a.w;
      ((float4*)beta)[m] = b;
    }
  }

  __threadfence();
  cg::this_grid().sync();

  // ===================== Phase B: RBF GEMM (old grid 2048) ================
#define LDFRAG(p)                                                      \
  ({                                                                   \
    int4 lo_ = *(const int4*)(p);                                      \
    int4 hi_ = *(const int4*)((p) + 8192);                             \
    (v8i){lo_.x, lo_.y, lo_.z, lo_.w, hi_.x, hi_.y, hi_.z, hi_.w};     \
  })
#define MFMA(a, b, c)                                                  \
  __builtin_amdgcn_mfma_scale_f32_16x16x128_f8f6f4(                    \
      (a), (b), (c), 0, 0, 0, 0x7f7f7f7f, 0, 0x7f7f7f7f)

  for (int gbx = blockIdx.x; gbx < 2048; gbx += gridDim.x) {
    int chunk = gbx & 63, nb = gbx >> 6;
    int wn = wave >> 1, wm = wave & 1;
    int col = lane & 15, quad = lane >> 4;
    int slot = quad ^ ((col >> 1) & 3);

    const u8* abase = feats_t + (size_t)nb * TILE_BYTES +
                      (wn * 64 + col) * 64 + slot * 16;
    const u8* bbase = sup_t + (size_t)chunk * TILE_BYTES +
                      (wm * 64 + col) * 64 + slot * 16;

    f32x4 acc[4][4];
#pragma unroll
    for (int i = 0; i < 4; i++)
#pragma unroll
      for (int j = 0; j < 4; j++) acc[i][j] = (f32x4){0, 0, 0, 0};

#pragma unroll 1
    for (int kk = 0; kk < 7; ++kk) {
      const u8* ak = abase + kk * 16384;
      const u8* bk = bbase + kk * 16384;
      // all 4 B-frags resident; A-frags ping-pong (R17-proven, VGPR=64)
      v8i bv0 = LDFRAG(bk);
      v8i bv1 = LDFRAG(bk + 1024);
      v8i bv2 = LDFRAG(bk + 2048);
      v8i bv3 = LDFRAG(bk + 3072);
      v8i a0 = LDFRAG(ak);
      v8i a1 = LDFRAG(ak + 1024);
      acc[0][0] = MFMA(a0, bv0, acc[0][0]);
      acc[0][1] = MFMA(a0, bv1, acc[0][1]);
      acc[0][2] = MFMA(a0, bv2, acc[0][2]);
      acc[0][3] = MFMA(a0, bv3, acc[0][3]);
      a0 = LDFRAG(ak + 2048);
      acc[1][0] = MFMA(a1, bv0, acc[1][0]);
      acc[1][1] = MFMA(a1, bv1, acc[1][1]);
      acc[1][2] = MFMA(a1, bv2, acc[1][2]);
      acc[1][3] = MFMA(a1, bv3, acc[1][3]);
      a1 = LDFRAG(ak + 3072);
      acc[2][0] = MFMA(a0, bv0, acc[2][0]);
      acc[2][1] = MFMA(a0, bv1, acc[2][1]);
      acc[2][2] = MFMA(a0, bv2, acc[2][2]);
      acc[2][3] = MFMA(a0, bv3, acc[2][3]);
      acc[3][0] = MFMA(a1, bv0, acc[3][0]);
      acc[3][1] = MFMA(a1, bv1, acc[3][1]);
      acc[3][2] = MFMA(a1, bv2, acc[3][2]);
      acc[3][3] = MFMA(a1, bv3, acc[3][3]);
    }

    // epilogue: Kv = exp(2*gamma*G), dot with beta, 16-lane reduce, store
#pragma unroll
    for (int i = 0; i < 4; i++)
#pragma unroll
      for (int j = 0; j < 4; j++) {
        acc[i][j].x = __expf(2.f * GAMMA * acc[i][j].x);
        acc[i][j].y = __expf(2.f * GAMMA * acc[i][j].y);
        acc[i][j].z = __expf(2.f * GAMMA * acc[i][j].z);
        acc[i][j].w = __expf(2.f * GAMMA * acc[i][j].w);
      }
    int n0 = nb * 128, m0 = chunk * 128;
#pragma unroll
    for (int c = 0; c < 4; ++c) {
      float bl[4];
#pragma unroll
      for (int j = 0; j < 4; j++)
        bl[j] = beta[(m0 + wm * 64 + j * 16 + col) * 4 + c];
#pragma unroll
      for (int i = 0; i < 4; i++) {
        f32x4 s = acc[i][0] * bl[0] + acc[i][1] * bl[1] + acc[i][2] * bl[2] +
                  acc[i][3] * bl[3];
#pragma unroll
        for (int st = 1; st < 16; st <<= 1) {
          s.x += __shfl_xor(s.x, st, 16);
          s.y += __shfl_xor(s.y, st, 16);
          s.z += __shfl_xor(s.z, st, 16);
          s.w += __shfl_xor(s.w, st, 16);
        }
        if (col == c) {
          int n = n0 + wn * 64 + i * 16 + quad * 4;
          float* pp = partial + (((size_t)chunk * 2 + wm) * 4096 + n) * 4 + c;
          pp[0] = s.x; pp[4] = s.y; pp[8] = s.z; pp[12] = s.w;
        }
      }
    }
  }
#undef LDFRAG
#undef MFMA

  __threadfence();
  cg::this_grid().sync();

  // ===================== Phase C: final reduce (256 block-slots) ==========
  {
    float4(*sred)[16] = (float4(*)[16])xp;  // alias conv LDS (done above)
    int nl = tid & 15, sg = tid >> 4;
    for (int rb = blockIdx.x; rb < 256; rb += gridDim.x) {
      int n = rb * 16 + nl;
      const float4* p = (const float4*)partial;
      float sx = 0, sy = 0, sz = 0, sw = 0;
#pragma unroll
      for (int ch = sg * 8; ch < sg * 8 + 8; ch++) {
        float4 v = p[(size_t)ch * 4096 + n];
        sx += v.x; sy += v.y; sz += v.z; sw += v.w;
      }
      sred[sg][nl] = (float4){sx, sy, sz, sw};
      __syncthreads();
      for (int st = 8; st > 0; st >>= 1) {
        if (sg < st) {
          float4 a = sred[sg][nl], b = sred[sg + st][nl];
          sred[sg][nl] = (float4){a.x + b.x, a.y + b.y, a.z + b.z, a.w + b.w};
        }
        __syncthreads();
      }
      if (sg == 0) {
        float e = ef[n];
        float4 a = sred[0][nl];
        ((float4*)out)[n] = (float4){e * a.x, e * a.y, e * a.z, e * a.w};
      }
      __syncthreads();  // LDS reuse if multiple rb iterations
    }
  }
}

// ---------------------------------------------------------------------------
// Fallback path: the R4-proven 3-kernel pipeline (used only if the
// cooperative launch is rejected by the runtime).
// ---------------------------------------------------------------------------
__global__ __launch_bounds__(256, 4) void conv_prep_kernel(
    const float* __restrict__ x, const float* __restrict__ w1,
    const float* __restrict__ b1, const float* __restrict__ w2,
    const float* __restrict__ b2, const float* __restrict__ support,
    const float* __restrict__ alpha, u8* __restrict__ feats_t,
    u8* __restrict__ sup_t, float* __restrict__ beta,
    float* __restrict__ ef) {
  int tid = threadIdx.x;
  int bx = blockIdx.x;

  if (bx >= 2048) {  // ---- support prep: wave per row ----
    int lane = tid & 63, wave = tid >> 6;
    int m = (bx - 2048) * 4 + wave;
    const float* row = support + (size_t)m * 784;
    int mt = m >> 7, mr = m & 127;
    u8* tb = sup_t + (size_t)mt * TILE_BYTES;
    float ss = 0.f;
    if (lane < 56) {
      uint4 w;
      if (lane < 49) {
        float4 f0 = ((const float4*)row)[lane * 4 + 0];
        float4 f1 = ((const float4*)row)[lane * 4 + 1];
        float4 f2 = ((const float4*)row)[lane * 4 + 2];
        float4 f3 = ((const float4*)row)[lane * 4 + 3];
        ss = f0.x * f0.x + f0.y * f0.y + f0.z * f0.z + f0.w * f0.w +
             f1.x * f1.x + f1.y * f1.y + f1.z * f1.z + f1.w * f1.w +
             f2.x * f2.x + f2.y * f2.y + f2.z * f2.z + f2.w * f2.w +
             f3.x * f3.x + f3.y * f3.y + f3.z * f3.z + f3.w * f3.w;
        w.x = pack4_fp8(f0); w.y = pack4_fp8(f1);
        w.z = pack4_fp8(f2); w.w = pack4_fp8(f3);
      } else {
        w.x = 0; w.y = 0; w.z = 0; w.w = 0;
      }
      int kk = lane >> 3, u = lane & 7, q = u >> 1, h = u & 1;
      int qs = q ^ ((mr >> 1) & 3);
      *(uint4*)(tb + kk * 16384 + h * 8192 + mr * 64 + qs * 16) = w;
    }
#pragma unroll
    for (int s = 1; s < 64; s <<= 1) ss += __shfl_xor(ss, s, 64);
    if (lane == 0) {
      float es = __expf(-GAMMA * ss);
      float4 a = ((const float4*)alpha)[m];
      float4 b;
      b.x = es * a.x; b.y = es * a.y; b.z = es * a.z; b.w = es * a.w;
      ((float4*)beta)[m] = b;
    }
    return;
  }

  __shared__ float xp[2][900];
  __shared__ alignas(16) ushort a1h[2][2048];
  __shared__ float w1s[72], b1s[8], b2s[16];
  __shared__ float w2s[1152];
  __shared__ alignas(8) ushort sc[2][16][212];
  __shared__ alignas(16) u8 fb[2][784];
  __shared__ float red[256];

  int lane = tid & 63, wave = tid >> 6;

  for (int t = tid; t < 1800; t += 256) ((float*)xp)[t] = 0.f;
  for (int t = tid; t < 1024; t += 256) ((uint4*)a1h)[t] = (uint4){0, 0, 0, 0};
  if (tid < 72) w1s[tid] = w1[tid];
  if (tid < 8) b1s[tid] = b1[tid];
  if (tid < 16) b2s[tid] = b2[tid];
  for (int t = tid; t < 1152; t += 256) w2s[t] = w2[t];
  __syncthreads();

  int oc = lane & 15, quad = lane >> 4;
  bh8 wf[3];
#pragma unroll
  for (int g = 0; g < 3; g++) {
    int tap = g * 4 + quad;
#pragma unroll
    for (int j = 0; j < 8; j++) {
      float v = (tap < 9) ? w2s[oc * 72 + j * 9 + tap] : 0.f;
      wf[g][j] = (short)bf16u(v);
    }
  }

  for (int t = tid; t < 392; t += 256) {
    int img = t >= 196, j = t - img * 196;
    float4 v = ((const float4*)(x + (size_t)(bx * 2 + img) * 784))[j];
    int r = j / 7, c = (j % 7) * 4;
    float* p = &xp[img][(r + 1) * 30 + (c + 1)];
    p[0] = v.x; p[1] = v.y; p[2] = v.z; p[3] = v.w;
  }
  __syncthreads();

  for (int idx = tid; idx < 3136; idx += 256) {
    int img = idx >= 1568;
    int rem = idx - img * 1568;
    int c = rem / 196, r2 = rem % 196;
    int ph = r2 / 14, pw = r2 % 14;
    const float* w = &w1s[c * 9];
    const float* xb = &xp[img][(2 * ph) * 30 + (2 * pw)];
    float t[4][4];
#pragma unroll
    for (int a = 0; a < 4; a++) {
      float2 u0 = *(const float2*)(xb + a * 30);
      float2 u1 = *(const float2*)(xb + a * 30 + 2);
      t[a][0] = u0.x; t[a][1] = u0.y; t[a][2] = u1.x; t[a][3] = u1.y;
    }
    float s00 = 0, s01 = 0, s10 = 0, s11 = 0;
#pragma unroll
    for (int dy = 0; dy < 3; dy++)
#pragma unroll
      for (int dx = 0; dx < 3; dx++) {
        float wv = w[dy * 3 + dx];
        s00 += t[dy][dx] * wv;     s01 += t[dy][dx + 1] * wv;
        s10 += t[dy + 1][dx] * wv; s11 += t[dy + 1][dx + 1] * wv;
      }
    float mx = fmaxf(fmaxf(s00, s01), fmaxf(s10, s11));
    float val = fmaxf(mx + b1s[c], 0.f);
    a1h[img][((ph + 1) * 16 + (pw + 1)) * 8 + c] = bf16u(val);
  }
  __syncthreads();

  {
    int img2 = wave >> 1, half = wave & 1;
    int Tstart = half * 7, Tcnt = half ? 6 : 7;
    const ushort* abase = a1h[img2];
    int mrow = lane & 15;
    for (int t = 0; t < Tcnt; ++t) {
      int T = Tstart + t;
      int p = T * 16 + mrow;
      int pc = p > 195 ? 195 : p;
      int y = pc / 14, xq = pc - y * 14;
      int cell = y * 16 + xq;
      f32x4 acc = (f32x4){0, 0, 0, 0};
#pragma unroll
      for (int g = 0; g < 3; g++) {
        int tap = g * 4 + quad;
        const ushort* ap;
        if (g == 2 && quad > 0) {
          ap = abase;
        } else {
          int dy = tap / 3, dx = tap - dy * 3;
          ap = abase + (cell + dy * 16 + dx) * 8;
        }
        bh8 af = *(const bh8*)ap;
        acc = __builtin_amdgcn_mfma_f32_16x16x32_bf16(af, wf[g], acc, 0, 0, 0);
      }
      int pos0 = T * 16 + quad * 4;
      ushort4 s4;
      s4.x = bf16u(acc.x); s4.y = bf16u(acc.y);
      s4.z = bf16u(acc.z); s4.w = bf16u(acc.w);
      *(ushort4*)(&sc[img2][oc][pos0]) = s4;
    }
  }
  __syncthreads();

  int img = tid >> 7, r = tid & 127;
  float fsq = 0.f;
  if (r < 112) {
    int o = r & 15, y7 = r >> 4;
    const ushort* srow = sc[img][o];
    float bo = b2s[o];
#pragma unroll
    for (int x7 = 0; x7 < 7; x7++) {
      int p = 28 * y7 + 2 * x7;
      unsigned u0 = *(const unsigned*)(&srow[p]);
      unsigned u1 = *(const unsigned*)(&srow[p + 14]);
      float a = __uint_as_float(u0 << 16);
      float b = __uint_as_float(u0 & 0xffff0000u);
      float c = __uint_as_float(u1 << 16);
      float d = __uint_as_float(u1 & 0xffff0000u);
      float mx = fmaxf(fmaxf(a, b), fmaxf(c, d));
      float val = fmaxf(mx + bo, 0.f);
      fb[img][o * 49 + y7 * 7 + x7] =
          (u8)(__builtin_amdgcn_cvt_pk_fp8_f32(val, 0.f, 0, false) & 0xff);
      fsq += val * val;
    }
  }
  red[tid] = fsq;
  __syncthreads();
  for (int s = 64; s > 0; s >>= 1) {
    if ((tid & 127) < s) red[tid] += red[tid + s];
    __syncthreads();
  }
  if ((tid & 127) == 0) ef[bx * 2 + img] = __expf(-GAMMA * red[tid]);

  if (tid < 112) {
    int im = tid >= 56, j = tid - im * 56;
    uint4 v;
    if (j < 49) v = ((const uint4*)fb[im])[j];
    else { v.x = 0; v.y = 0; v.z = 0; v.w = 0; }
    int n = bx * 2 + im;
    int nt = n >> 7, nr = n & 127;
    int kk = j >> 3, u = j & 7, q = u >> 1, h = u & 1;
    int qs = q ^ ((nr >> 1) & 3);
    *(uint4*)(feats_t + (size_t)nt * TILE_BYTES + kk * 16384 + h * 8192 +
              nr * 64 + qs * 16) = v;
  }
}

__global__ __launch_bounds__(256, 4) void rbf_gemm_kernel(
    const u8* __restrict__ feats_t, const u8* __restrict__ sup_t,
    const float* __restrict__ beta, float* __restrict__ partial) {
  int tid = threadIdx.x;
  int wave = tid >> 6, lane = tid & 63;
  int bx = blockIdx.x;
  int chunk = bx & 63, nb = bx >> 6;
  int wn = wave >> 1, wm = wave & 1;
  int col = lane & 15, quad = lane >> 4;
  int slot = quad ^ ((col >> 1) & 3);

  const u8* abase = feats_t + (size_t)nb * TILE_BYTES +
                    (wn * 64 + col) * 64 + slot * 16;
  const u8* bbase = sup_t + (size_t)chunk * TILE_BYTES +
                    (wm * 64 + col) * 64 + slot * 16;

  f32x4 acc[4][4];
#pragma unroll
  for (int i = 0; i < 4; i++)
#pragma unroll
    for (int j = 0; j < 4; j++) acc[i][j] = (f32x4){0, 0, 0, 0};

#define LDFRAG(p)                                                      \
  ({                                                                   \
    int4 lo_ = *(const int4*)(p);                                      \
    int4 hi_ = *(const int4*)((p) + 8192);                             \
    (v8i){lo_.x, lo_.y, lo_.z, lo_.w, hi_.x, hi_.y, hi_.z, hi_.w};     \
  })
#define MFMA(a, b, c)                                                  \
  __builtin_amdgcn_mfma_scale_f32_16x16x128_f8f6f4(                    \
      (a), (b), (c), 0, 0, 0, 0x7f7f7f7f, 0, 0x7f7f7f7f)

#pragma unroll 1
  for (int kk = 0; kk < 7; ++kk) {
    const u8* ak = abase + kk * 16384;
    const u8* bk = bbase + kk * 16384;
    v8i bv0 = LDFRAG(bk);
    v8i bv1 = LDFRAG(bk + 1024);
    v8i bv2 = LDFRAG(bk + 2048);
    v8i bv3 = LDFRAG(bk + 3072);
    v8i a0 = LDFRAG(ak);
    v8i a1 = LDFRAG(ak + 1024);
    acc[0][0] = MFMA(a0, bv0, acc[0][0]);
    acc[0][1] = MFMA(a0, bv1, acc[0][1]);
    acc[0][2] = MFMA(a0, bv2, acc[0][2]);
    acc[0][3] = MFMA(a0, bv3, acc[0][3]);
    a0 = LDFRAG(ak + 2048);
    acc[1][0] = MFMA(a1, bv0, acc[1][0]);
    acc[1][1] = MFMA(a1, bv1, acc[1][1]);
    acc[1][2] = MFMA(a1, bv2, acc[1][2]);
    acc[1][3] = MFMA(a1, bv3, acc[1][3]);
    a1 = LDFRAG(ak + 3072);
    acc[2][0] = MFMA(a0, bv0, acc[2][0]);
    acc[2][1] = MFMA(a0, bv1, acc[2][1]);
    acc[2][2] = MFMA(a0, bv2, acc[2][2]);
    acc[2][3] = MFMA(a0, bv3, acc[2][3]);
    acc[3][0] = MFMA(a1, bv0, acc[3][0]);
    acc[3][1] = MFMA(a1, bv1, acc[3][1]);
    acc[3][2] = MFMA(a1, bv2, acc[3][2]);
    acc[3][3] = MFMA(a1, bv3, acc[3][3]);
  }
#undef LDFRAG
#undef MFMA

#pragma unroll
  for (int i = 0; i < 4; i++)
#pragma unroll
    for (int j = 0; j < 4; j++) {
      acc[i][j].x = __expf(2.f * GAMMA * acc[i][j].x);
      acc[i][j].y = __expf(2.f * GAMMA * acc[i][j].y);
      acc[i][j].z = __expf(2.f * GAMMA * acc[i][j].z);
      acc[i][j].w = __expf(2.f * GAMMA * acc[i][j].w);
    }
  int n0 = nb * 128, m0 = chunk * 128;
#pragma unroll
  for (int c = 0; c < 4; ++c) {
    float bl[4];
#pragma unroll
    for (int j = 0; j < 4; j++)
      bl[j] = beta[(m0 + wm * 64 + j * 16 + col) * 4 + c];
#pragma unroll
    for (int i = 0; i < 4; i++) {
      f32x4 s = acc[i][0] * bl[0] + acc[i][1] * bl[1] + acc[i][2] * bl[2] +
                acc[i][3] * bl[3];
#pragma unroll
      for (int st = 1; st < 16; st <<= 1) {
        s.x += __shfl_xor(s.x, st, 16);
        s.y += __shfl_xor(s.y, st, 16);
        s.z += __shfl_xor(s.z, st, 16);
        s.w += __shfl_xor(s.w, st, 16);
      }
      if (col == c) {
        int n = n0 + wn * 64 + i * 16 + quad * 4;
        float* pp = partial + (((size_t)chunk * 2 + wm) * 4096 + n) * 4 + c;
        pp[0] = s.x; pp[4] = s.y; pp[8] = s.z; pp[12] = s.w;
      }
    }
  }
}

__global__ __launch_bounds__(256) void reduce_kernel(
    const float* __restrict__ partial, const float* __restrict__ ef,
    float* __restrict__ out) {
  __shared__ float4 sred[16][16];
  int nl = threadIdx.x & 15, sg = threadIdx.x >> 4;
  int n = blockIdx.x * 16 + nl;
  const float4* p = (const float4*)partial;
  float sx = 0, sy = 0, sz = 0, sw = 0;
#pragma unroll
  for (int ch = sg * 8; ch < sg * 8 + 8; ch++) {
    float4 v = p[(size_t)ch * 4096 + n];
    sx += v.x; sy += v.y; sz += v.z; sw += v.w;
  }
  sred[sg][nl] = (float4){sx, sy, sz, sw};
  __syncthreads();
  for (int st = 8; st > 0; st >>= 1) {
    if (sg < st) {
      float4 a = sred[sg][nl], b = sred[sg + st][nl];
      sred[sg][nl] = (float4){a.x + b.x, a.y + b.y, a.z + b.z, a.w + b.w};
    }
    __syncthreads();
  }
  if (sg == 0) {
    float e = ef[n];
    float4 a = sred[0][nl];
    ((float4*)out)[n] = (float4){e * a.x, e * a.y, e * a.z, e * a.w};
  }
}

// ---------------------------------------------------------------------------
extern "C" void kernel_launch(void* const* d_in, const int* in_sizes, int n_in,
                              void* d_out, int out_size, void* d_ws,
                              size_t ws_size, hipStream_t stream) {
  const float* x = (const float*)d_in[0];
  const float* w1 = (const float*)d_in[1];
  const float* b1 = (const float*)d_in[2];
  const float* w2 = (const float*)d_in[3];
  const float* b2 = (const float*)d_in[4];
  const float* support = (const float*)d_in[5];
  const float* alpha = (const float*)d_in[6];
  float* out = (float*)d_out;

  u8* ws = (u8*)d_ws;
  u8* sup_t = ws;                                 // 64 tiles  = 7,340,032 B
  u8* feats_t = ws + 7340032;                     // 32 tiles  = 3,670,016 B
  float* beta = (float*)(ws + 11010048);          // 8192*4*4  =   131,072 B
  float* ef = (float*)(ws + 11141120);            // 4096*4    =    16,384 B
  float* partial = (float*)(ws + 11157504);       // 128*4096*4*4 = 8,388,608 B

  // grid = co-resident capacity (multiple of 64 preserves chunk->XCD map)
  static int coop_grid = 0;
  if (coop_grid == 0) {
    int per_cu = 0;
    if (hipOccupancyMaxActiveBlocksPerMultiprocessor(
            &per_cu, (const void*)fused_kernel, 256, 0) != hipSuccess ||
        per_cu <= 0)
      per_cu = 2;
    if (per_cu > 4) per_cu = 4;
    coop_grid = per_cu * 256;
    if (coop_grid > 1024) coop_grid = 1024;
    if (coop_grid < 256) coop_grid = 256;
  }

  void* kargs[] = {(void*)&x,       (void*)&w1,      (void*)&b1,
                   (void*)&w2,      (void*)&b2,      (void*)&support,
                   (void*)&alpha,   (void*)&feats_t, (void*)&sup_t,
                   (void*)&beta,    (void*)&ef,      (void*)&partial,
                   (void*)&out};
  hipError_t err = hipLaunchCooperativeKernel(
      (const void*)fused_kernel, dim3(coop_grid), dim3(256), kargs, 0, stream);
  if (err != hipSuccess) {
    (void)hipGetLastError();  // clear
    conv_prep_kernel<<<4096, 256, 0, stream>>>(x, w1, b1, w2, b2, support,
                                               alpha, feats_t, sup_t, beta,
                                               ef);
    rbf_gemm_kernel<<<2048, 256, 0, stream>>>(feats_t, sup_t, beta, partial);
    reduce_kernel<<<256, 256, 0, stream>>>(partial, ef, out);
  }
}

// Round 6
// 391.417 us; speedup vs baseline: 1.1571x; 1.1571x over previous
//
#include <hip/hip_runtime.h>
#include <hip/hip_bf16.h>
#include <hip/hip_cooperative_groups.h>
#include <cstdint>

namespace cg = cooperative_groups;

#define GAMMA 0.001f
// K padded 784 -> 896 = 7*128. Swizzled fp8 tile layout per 128-row tile
// (R8/R9-proven): addr = tile*114688 + kk*16384 + h*8192 + row*64
//                        + (q ^ ((row>>1)&3))*16
// where source byte k = kk*128 + q*32 + h*16 + [0..15].
#define TILE_BYTES 114688

typedef __attribute__((ext_vector_type(4))) float f32x4;
typedef __attribute__((ext_vector_type(8))) int v8i;
typedef __attribute__((ext_vector_type(8))) short bh8;  // 8 bf16
typedef unsigned char u8;

__device__ inline unsigned pack4_fp8(float4 f) {
  unsigned p = __builtin_amdgcn_cvt_pk_fp8_f32(f.x, f.y, 0, false);
  p = __builtin_amdgcn_cvt_pk_fp8_f32(f.z, f.w, p, true);
  return p;
}

__device__ inline ushort bf16u(float v) {
  __hip_bfloat16 h = __float2bfloat16(v);
  return *(ushort*)&h;
}

// ---------------------------------------------------------------------------
// R19: FUSED cooperative kernel, SPILL FIXED. R5's fusion at (256,4) spilled
// (128 VGPR/wave budget < conv+gemm peak): WRITE 33MB (=13MB scratch stores),
// MfmaUtil 2.2%, 577us — scratch-latency-bound. Fix: launch_bounds(256,3)
// -> 168 VGPR/wave; gemm needs 128 (64 acc + 64 operands), conv ~120-150,
// both fit. Occupancy 3/CU (gemm ~56us vs 53 at 4/CU — acceptable trade).
// Grid = per_cu*256 (multiple of 64 preserves chunk->XCD map AND makes each
// block reuse the SAME B-chunk across its gemm iterations).
// SPILL TRIPWIRE: WRITE_SIZE must be ~20MB. If >30MB -> spilled again.
// Phase bodies byte-identical to the R4-proven kernels.
// ---------------------------------------------------------------------------
__global__ __launch_bounds__(256, 3) void fused_kernel(
    const float* __restrict__ x, const float* __restrict__ w1,
    const float* __restrict__ b1, const float* __restrict__ w2,
    const float* __restrict__ b2, const float* __restrict__ support,
    const float* __restrict__ alpha, u8* __restrict__ feats_t,
    u8* __restrict__ sup_t, float* __restrict__ beta, float* __restrict__ ef,
    float* __restrict__ partial, float* __restrict__ out) {
  __shared__ alignas(16) float xp[2][900];     // 30x30 zero-padded input
  __shared__ alignas(16) ushort a1h[2][2048];  // HWC bf16: (row*16+col)*8+ic
  __shared__ float w1s[72], b1s[8], b2s[16];
  __shared__ float w2s[1152];                  // raw w2 [oc][ic][9]
  __shared__ alignas(8) ushort sc[2][16][212]; // conv2 out bf16 [oc][pos]
  __shared__ alignas(16) u8 fb[2][784];
  __shared__ float red[256];

  int tid = threadIdx.x;
  int lane = tid & 63, wave = tid >> 6;

  // ===================== Phase A1: conv pairs (old bx 0..2047) ============
  for (int cbx = blockIdx.x; cbx < 2048; cbx += gridDim.x) {
    __syncthreads();  // LDS reuse across iterations

    for (int t = tid; t < 1800; t += 256) ((float*)xp)[t] = 0.f;
    for (int t = tid; t < 1024; t += 256)
      ((uint4*)a1h)[t] = (uint4){0, 0, 0, 0};
    if (tid < 72) w1s[tid] = w1[tid];
    if (tid < 8) b1s[tid] = b1[tid];
    if (tid < 16) b2s[tid] = b2[tid];
    for (int t = tid; t < 1152; t += 256) w2s[t] = w2[t];
    __syncthreads();

    // per-lane B-frags (weights): oc=lane&15, k=(tap=g*4+quad, ic=j)
    int oc = lane & 15, quad = lane >> 4;
    bh8 wf[3];
#pragma unroll
    for (int g = 0; g < 3; g++) {
      int tap = g * 4 + quad;
#pragma unroll
      for (int j = 0; j < 8; j++) {
        float v = (tap < 9) ? w2s[oc * 72 + j * 9 + tap] : 0.f;
        wf[g][j] = (short)bf16u(v);
      }
    }

    for (int t = tid; t < 392; t += 256) {
      int img = t >= 196, j = t - img * 196;
      float4 v = ((const float4*)(x + (size_t)(cbx * 2 + img) * 784))[j];
      int r = j / 7, c = (j % 7) * 4;
      float* p = &xp[img][(r + 1) * 30 + (c + 1)];
      p[0] = v.x; p[1] = v.y; p[2] = v.z; p[3] = v.w;
    }
    __syncthreads();

    // stage 1: conv1+bias+relu+maxpool2 -> a1h (HWC bf16) interiors
    for (int idx = tid; idx < 3136; idx += 256) {
      int img = idx >= 1568;
      int rem = idx - img * 1568;
      int c = rem / 196, r2 = rem % 196;
      int ph = r2 / 14, pw = r2 % 14;
      const float* w = &w1s[c * 9];
      const float* xb = &xp[img][(2 * ph) * 30 + (2 * pw)];
      float t[4][4];
#pragma unroll
      for (int a = 0; a < 4; a++) {
        float2 u0 = *(const float2*)(xb + a * 30);
        float2 u1 = *(const float2*)(xb + a * 30 + 2);
        t[a][0] = u0.x; t[a][1] = u0.y; t[a][2] = u1.x; t[a][3] = u1.y;
      }
      float s00 = 0, s01 = 0, s10 = 0, s11 = 0;
#pragma unroll
      for (int dy = 0; dy < 3; dy++)
#pragma unroll
        for (int dx = 0; dx < 3; dx++) {
          float wv = w[dy * 3 + dx];
          s00 += t[dy][dx] * wv;     s01 += t[dy][dx + 1] * wv;
          s10 += t[dy + 1][dx] * wv; s11 += t[dy + 1][dx + 1] * wv;
        }
      float mx = fmaxf(fmaxf(s00, s01), fmaxf(s10, s11));
      float val = fmaxf(mx + b1s[c], 0.f);
      a1h[img][((ph + 1) * 16 + (pw + 1)) * 8 + c] = bf16u(val);
    }
    __syncthreads();

    // stage 2 (MFMA): waves 0,1 -> img0; waves 2,3 -> img1.
    {
      int img2 = wave >> 1, half = wave & 1;
      int Tstart = half * 7, Tcnt = half ? 6 : 7;
      const ushort* abase = a1h[img2];
      int mrow = lane & 15;
      for (int t = 0; t < Tcnt; ++t) {
        int T = Tstart + t;
        int p = T * 16 + mrow;
        int pc = p > 195 ? 195 : p;
        int y = pc / 14, xq = pc - y * 14;
        int cell = y * 16 + xq;
        f32x4 acc = (f32x4){0, 0, 0, 0};
#pragma unroll
        for (int g = 0; g < 3; g++) {
          int tap = g * 4 + quad;
          const ushort* ap;
          if (g == 2 && quad > 0) {
            ap = abase;  // border cell (0,0): guaranteed zeros
          } else {
            int dy = tap / 3, dx = tap - dy * 3;
            ap = abase + (cell + dy * 16 + dx) * 8;
          }
          bh8 af = *(const bh8*)ap;
          acc =
              __builtin_amdgcn_mfma_f32_16x16x32_bf16(af, wf[g], acc, 0, 0, 0);
        }
        int pos0 = T * 16 + quad * 4;
        ushort4 s4;
        s4.x = bf16u(acc.x); s4.y = bf16u(acc.y);
        s4.z = bf16u(acc.z); s4.w = bf16u(acc.w);
        *(ushort4*)(&sc[img2][oc][pos0]) = s4;
      }
    }
    __syncthreads();

    // pooling + bias + relu + fp8 + fsq from sc
    int img = tid >> 7, r = tid & 127;
    float fsq = 0.f;
    if (r < 112) {
      int o = r & 15, y7 = r >> 4;
      const ushort* srow = sc[img][o];
      float bo = b2s[o];
#pragma unroll
      for (int x7 = 0; x7 < 7; x7++) {
        int p = 28 * y7 + 2 * x7;
        unsigned u0 = *(const unsigned*)(&srow[p]);
        unsigned u1 = *(const unsigned*)(&srow[p + 14]);
        float a = __uint_as_float(u0 << 16);
        float b = __uint_as_float(u0 & 0xffff0000u);
        float c = __uint_as_float(u1 << 16);
        float d = __uint_as_float(u1 & 0xffff0000u);
        float mx = fmaxf(fmaxf(a, b), fmaxf(c, d));
        float val = fmaxf(mx + bo, 0.f);
        fb[img][o * 49 + y7 * 7 + x7] =
            (u8)(__builtin_amdgcn_cvt_pk_fp8_f32(val, 0.f, 0, false) & 0xff);
        fsq += val * val;
      }
    }
    red[tid] = fsq;
    __syncthreads();
    for (int s = 64; s > 0; s >>= 1) {
      if ((tid & 127) < s) red[tid] += red[tid + s];
      __syncthreads();
    }
    if ((tid & 127) == 0) ef[cbx * 2 + img] = __expf(-GAMMA * red[tid]);

    // store feats: 2 imgs x 56 16B-units into swizzled tile layout
    if (tid < 112) {
      int im = tid >= 56, j = tid - im * 56;
      uint4 v;
      if (j < 49) v = ((const uint4*)fb[im])[j];
      else { v.x = 0; v.y = 0; v.z = 0; v.w = 0; }
      int n = cbx * 2 + im;
      int nt = n >> 7, nr = n & 127;
      int kk = j >> 3, u = j & 7, q = u >> 1, h = u & 1;
      int qs = q ^ ((nr >> 1) & 3);
      *(uint4*)(feats_t + (size_t)nt * TILE_BYTES + kk * 16384 + h * 8192 +
                nr * 64 + qs * 16) = v;
    }
  }

  // ===================== Phase A2: support prep (8192 rows) ===============
  for (int sb = blockIdx.x; sb < 2048; sb += gridDim.x) {
    int m = sb * 4 + wave;
    const float* row = support + (size_t)m * 784;
    int mt = m >> 7, mr = m & 127;
    u8* tb = sup_t + (size_t)mt * TILE_BYTES;
    float ss = 0.f;
    if (lane < 56) {  // 16B unit j covers source bytes 16j..16j+15
      uint4 w;
      if (lane < 49) {
        float4 f0 = ((const float4*)row)[lane * 4 + 0];
        float4 f1 = ((const float4*)row)[lane * 4 + 1];
        float4 f2 = ((const float4*)row)[lane * 4 + 2];
        float4 f3 = ((const float4*)row)[lane * 4 + 3];
        ss = f0.x * f0.x + f0.y * f0.y + f0.z * f0.z + f0.w * f0.w +
             f1.x * f1.x + f1.y * f1.y + f1.z * f1.z + f1.w * f1.w +
             f2.x * f2.x + f2.y * f2.y + f2.z * f2.z + f2.w * f2.w +
             f3.x * f3.x + f3.y * f3.y + f3.z * f3.z + f3.w * f3.w;
        w.x = pack4_fp8(f0); w.y = pack4_fp8(f1);
        w.z = pack4_fp8(f2); w.w = pack4_fp8(f3);
      } else {
        w.x = 0; w.y = 0; w.z = 0; w.w = 0;
      }
      int kk = lane >> 3, u = lane & 7, q = u >> 1, h = u & 1;
      int qs = q ^ ((mr >> 1) & 3);
      *(uint4*)(tb + kk * 16384 + h * 8192 + mr * 64 + qs * 16) = w;
    }
#pragma unroll
    for (int s = 1; s < 64; s <<= 1) ss += __shfl_xor(ss, s, 64);
    if (lane == 0) {
      float es = __expf(-GAMMA * ss);
      float4 a = ((const float4*)alpha)[m];
      float4 b;
      b.x = es * a.x; b.y = es * a.y; b.z = es * a.z; b.w = es * a.w;
      ((float4*)beta)[m] = b;
    }
  }

  __threadfence();
  cg::this_grid().sync();

  // ===================== Phase B: RBF GEMM (old grid 2048) ================
#define LDFRAG(p)                                                      \
  ({                                                                   \
    int4 lo_ = *(const int4*)(p);                                      \
    int4 hi_ = *(const int4*)((p) + 8192);                             \
    (v8i){lo_.x, lo_.y, lo_.z, lo_.w, hi_.x, hi_.y, hi_.z, hi_.w};     \
  })
#define MFMA(a, b, c)                                                  \
  __builtin_amdgcn_mfma_scale_f32_16x16x128_f8f6f4(                    \
      (a), (b), (c), 0, 0, 0, 0x7f7f7f7f, 0, 0x7f7f7f7f)

  for (int gbx = blockIdx.x; gbx < 2048; gbx += gridDim.x) {
    int chunk = gbx & 63, nb = gbx >> 6;
    int wn = wave >> 1, wm = wave & 1;
    int col = lane & 15, quad = lane >> 4;
    int slot = quad ^ ((col >> 1) & 3);

    const u8* abase = feats_t + (size_t)nb * TILE_BYTES +
                      (wn * 64 + col) * 64 + slot * 16;
    const u8* bbase = sup_t + (size_t)chunk * TILE_BYTES +
                      (wm * 64 + col) * 64 + slot * 16;

    f32x4 acc[4][4];
#pragma unroll
    for (int i = 0; i < 4; i++)
#pragma unroll
      for (int j = 0; j < 4; j++) acc[i][j] = (f32x4){0, 0, 0, 0};

#pragma unroll 1
    for (int kk = 0; kk < 7; ++kk) {
      const u8* ak = abase + kk * 16384;
      const u8* bk = bbase + kk * 16384;
      // all 4 B-frags resident; A-frags ping-pong (R17-proven)
      v8i bv0 = LDFRAG(bk);
      v8i bv1 = LDFRAG(bk + 1024);
      v8i bv2 = LDFRAG(bk + 2048);
      v8i bv3 = LDFRAG(bk + 3072);
      v8i a0 = LDFRAG(ak);
      v8i a1 = LDFRAG(ak + 1024);
      acc[0][0] = MFMA(a0, bv0, acc[0][0]);
      acc[0][1] = MFMA(a0, bv1, acc[0][1]);
      acc[0][2] = MFMA(a0, bv2, acc[0][2]);
      acc[0][3] = MFMA(a0, bv3, acc[0][3]);
      a0 = LDFRAG(ak + 2048);
      acc[1][0] = MFMA(a1, bv0, acc[1][0]);
      acc[1][1] = MFMA(a1, bv1, acc[1][1]);
      acc[1][2] = MFMA(a1, bv2, acc[1][2]);
      acc[1][3] = MFMA(a1, bv3, acc[1][3]);
      a1 = LDFRAG(ak + 3072);
      acc[2][0] = MFMA(a0, bv0, acc[2][0]);
      acc[2][1] = MFMA(a0, bv1, acc[2][1]);
      acc[2][2] = MFMA(a0, bv2, acc[2][2]);
      acc[2][3] = MFMA(a0, bv3, acc[2][3]);
      acc[3][0] = MFMA(a1, bv0, acc[3][0]);
      acc[3][1] = MFMA(a1, bv1, acc[3][1]);
      acc[3][2] = MFMA(a1, bv2, acc[3][2]);
      acc[3][3] = MFMA(a1, bv3, acc[3][3]);
    }

    // epilogue: Kv = exp(2*gamma*G), dot with beta, 16-lane reduce, store
#pragma unroll
    for (int i = 0; i < 4; i++)
#pragma unroll
      for (int j = 0; j < 4; j++) {
        acc[i][j].x = __expf(2.f * GAMMA * acc[i][j].x);
        acc[i][j].y = __expf(2.f * GAMMA * acc[i][j].y);
        acc[i][j].z = __expf(2.f * GAMMA * acc[i][j].z);
        acc[i][j].w = __expf(2.f * GAMMA * acc[i][j].w);
      }
    int n0 = nb * 128, m0 = chunk * 128;
#pragma unroll
    for (int c = 0; c < 4; ++c) {
      float bl[4];
#pragma unroll
      for (int j = 0; j < 4; j++)
        bl[j] = beta[(m0 + wm * 64 + j * 16 + col) * 4 + c];
#pragma unroll
      for (int i = 0; i < 4; i++) {
        f32x4 s = acc[i][0] * bl[0] + acc[i][1] * bl[1] + acc[i][2] * bl[2] +
                  acc[i][3] * bl[3];
#pragma unroll
        for (int st = 1; st < 16; st <<= 1) {
          s.x += __shfl_xor(s.x, st, 16);
          s.y += __shfl_xor(s.y, st, 16);
          s.z += __shfl_xor(s.z, st, 16);
          s.w += __shfl_xor(s.w, st, 16);
        }
        if (col == c) {
          int n = n0 + wn * 64 + i * 16 + quad * 4;
          float* pp = partial + (((size_t)chunk * 2 + wm) * 4096 + n) * 4 + c;
          pp[0] = s.x; pp[4] = s.y; pp[8] = s.z; pp[12] = s.w;
        }
      }
    }
  }
#undef LDFRAG
#undef MFMA

  __threadfence();
  cg::this_grid().sync();

  // ===================== Phase C: final reduce (256 block-slots) ==========
  {
    float4(*sred)[16] = (float4(*)[16])xp;  // alias conv LDS (done above)
    int nl = tid & 15, sg = tid >> 4;
    for (int rb = blockIdx.x; rb < 256; rb += gridDim.x) {
      int n = rb * 16 + nl;
      const float4* p = (const float4*)partial;
      float sx = 0, sy = 0, sz = 0, sw = 0;
#pragma unroll
      for (int ch = sg * 8; ch < sg * 8 + 8; ch++) {
        float4 v = p[(size_t)ch * 4096 + n];
        sx += v.x; sy += v.y; sz += v.z; sw += v.w;
      }
      sred[sg][nl] = (float4){sx, sy, sz, sw};
      __syncthreads();
      for (int st = 8; st > 0; st >>= 1) {
        if (sg < st) {
          float4 a = sred[sg][nl], b = sred[sg + st][nl];
          sred[sg][nl] = (float4){a.x + b.x, a.y + b.y, a.z + b.z, a.w + b.w};
        }
        __syncthreads();
      }
      if (sg == 0) {
        float e = ef[n];
        float4 a = sred[0][nl];
        ((float4*)out)[n] = (float4){e * a.x, e * a.y, e * a.z, e * a.w};
      }
      __syncthreads();  // LDS reuse if multiple rb iterations
    }
  }
}

// ---------------------------------------------------------------------------
// Fallback path: the R4-proven 3-kernel pipeline (used only if the
// cooperative launch is rejected by the runtime).
// ---------------------------------------------------------------------------
__global__ __launch_bounds__(256, 4) void conv_prep_kernel(
    const float* __restrict__ x, const float* __restrict__ w1,
    const float* __restrict__ b1, const float* __restrict__ w2,
    const float* __restrict__ b2, const float* __restrict__ support,
    const float* __restrict__ alpha, u8* __restrict__ feats_t,
    u8* __restrict__ sup_t, float* __restrict__ beta,
    float* __restrict__ ef) {
  int tid = threadIdx.x;
  int bx = blockIdx.x;

  if (bx >= 2048) {  // ---- support prep: wave per row ----
    int lane = tid & 63, wave = tid >> 6;
    int m = (bx - 2048) * 4 + wave;
    const float* row = support + (size_t)m * 784;
    int mt = m >> 7, mr = m & 127;
    u8* tb = sup_t + (size_t)mt * TILE_BYTES;
    float ss = 0.f;
    if (lane < 56) {
      uint4 w;
      if (lane < 49) {
        float4 f0 = ((const float4*)row)[lane * 4 + 0];
        float4 f1 = ((const float4*)row)[lane * 4 + 1];
        float4 f2 = ((const float4*)row)[lane * 4 + 2];
        float4 f3 = ((const float4*)row)[lane * 4 + 3];
        ss = f0.x * f0.x + f0.y * f0.y + f0.z * f0.z + f0.w * f0.w +
             f1.x * f1.x + f1.y * f1.y + f1.z * f1.z + f1.w * f1.w +
             f2.x * f2.x + f2.y * f2.y + f2.z * f2.z + f2.w * f2.w +
             f3.x * f3.x + f3.y * f3.y + f3.z * f3.z + f3.w * f3.w;
        w.x = pack4_fp8(f0); w.y = pack4_fp8(f1);
        w.z = pack4_fp8(f2); w.w = pack4_fp8(f3);
      } else {
        w.x = 0; w.y = 0; w.z = 0; w.w = 0;
      }
      int kk = lane >> 3, u = lane & 7, q = u >> 1, h = u & 1;
      int qs = q ^ ((mr >> 1) & 3);
      *(uint4*)(tb + kk * 16384 + h * 8192 + mr * 64 + qs * 16) = w;
    }
#pragma unroll
    for (int s = 1; s < 64; s <<= 1) ss += __shfl_xor(ss, s, 64);
    if (lane == 0) {
      float es = __expf(-GAMMA * ss);
      float4 a = ((const float4*)alpha)[m];
      float4 b;
      b.x = es * a.x; b.y = es * a.y; b.z = es * a.z; b.w = es * a.w;
      ((float4*)beta)[m] = b;
    }
    return;
  }

  __shared__ float xp[2][900];
  __shared__ alignas(16) ushort a1h[2][2048];
  __shared__ float w1s[72], b1s[8], b2s[16];
  __shared__ float w2s[1152];
  __shared__ alignas(8) ushort sc[2][16][212];
  __shared__ alignas(16) u8 fb[2][784];
  __shared__ float red[256];

  int lane = tid & 63, wave = tid >> 6;

  for (int t = tid; t < 1800; t += 256) ((float*)xp)[t] = 0.f;
  for (int t = tid; t < 1024; t += 256) ((uint4*)a1h)[t] = (uint4){0, 0, 0, 0};
  if (tid < 72) w1s[tid] = w1[tid];
  if (tid < 8) b1s[tid] = b1[tid];
  if (tid < 16) b2s[tid] = b2[tid];
  for (int t = tid; t < 1152; t += 256) w2s[t] = w2[t];
  __syncthreads();

  int oc = lane & 15, quad = lane >> 4;
  bh8 wf[3];
#pragma unroll
  for (int g = 0; g < 3; g++) {
    int tap = g * 4 + quad;
#pragma unroll
    for (int j = 0; j < 8; j++) {
      float v = (tap < 9) ? w2s[oc * 72 + j * 9 + tap] : 0.f;
      wf[g][j] = (short)bf16u(v);
    }
  }

  for (int t = tid; t < 392; t += 256) {
    int img = t >= 196, j = t - img * 196;
    float4 v = ((const float4*)(x + (size_t)(bx * 2 + img) * 784))[j];
    int r = j / 7, c = (j % 7) * 4;
    float* p = &xp[img][(r + 1) * 30 + (c + 1)];
    p[0] = v.x; p[1] = v.y; p[2] = v.z; p[3] = v.w;
  }
  __syncthreads();

  for (int idx = tid; idx < 3136; idx += 256) {
    int img = idx >= 1568;
    int rem = idx - img * 1568;
    int c = rem / 196, r2 = rem % 196;
    int ph = r2 / 14, pw = r2 % 14;
    const float* w = &w1s[c * 9];
    const float* xb = &xp[img][(2 * ph) * 30 + (2 * pw)];
    float t[4][4];
#pragma unroll
    for (int a = 0; a < 4; a++) {
      float2 u0 = *(const float2*)(xb + a * 30);
      float2 u1 = *(const float2*)(xb + a * 30 + 2);
      t[a][0] = u0.x; t[a][1] = u0.y; t[a][2] = u1.x; t[a][3] = u1.y;
    }
    float s00 = 0, s01 = 0, s10 = 0, s11 = 0;
#pragma unroll
    for (int dy = 0; dy < 3; dy++)
#pragma unroll
      for (int dx = 0; dx < 3; dx++) {
        float wv = w[dy * 3 + dx];
        s00 += t[dy][dx] * wv;     s01 += t[dy][dx + 1] * wv;
        s10 += t[dy + 1][dx] * wv; s11 += t[dy + 1][dx + 1] * wv;
      }
    float mx = fmaxf(fmaxf(s00, s01), fmaxf(s10, s11));
    float val = fmaxf(mx + b1s[c], 0.f);
    a1h[img][((ph + 1) * 16 + (pw + 1)) * 8 + c] = bf16u(val);
  }
  __syncthreads();

  {
    int img2 = wave >> 1, half = wave & 1;
    int Tstart = half * 7, Tcnt = half ? 6 : 7;
    const ushort* abase = a1h[img2];
    int mrow = lane & 15;
    for (int t = 0; t < Tcnt; ++t) {
      int T = Tstart + t;
      int p = T * 16 + mrow;
      int pc = p > 195 ? 195 : p;
      int y = pc / 14, xq = pc - y * 14;
      int cell = y * 16 + xq;
      f32x4 acc = (f32x4){0, 0, 0, 0};
#pragma unroll
      for (int g = 0; g < 3; g++) {
        int tap = g * 4 + quad;
        const ushort* ap;
        if (g == 2 && quad > 0) {
          ap = abase;
        } else {
          int dy = tap / 3, dx = tap - dy * 3;
          ap = abase + (cell + dy * 16 + dx) * 8;
        }
        bh8 af = *(const bh8*)ap;
        acc = __builtin_amdgcn_mfma_f32_16x16x32_bf16(af, wf[g], acc, 0, 0, 0);
      }
      int pos0 = T * 16 + quad * 4;
      ushort4 s4;
      s4.x = bf16u(acc.x); s4.y = bf16u(acc.y);
      s4.z = bf16u(acc.z); s4.w = bf16u(acc.w);
      *(ushort4*)(&sc[img2][oc][pos0]) = s4;
    }
  }
  __syncthreads();

  int img = tid >> 7, r = tid & 127;
  float fsq = 0.f;
  if (r < 112) {
    int o = r & 15, y7 = r >> 4;
    const ushort* srow = sc[img][o];
    float bo = b2s[o];
#pragma unroll
    for (int x7 = 0; x7 < 7; x7++) {
      int p = 28 * y7 + 2 * x7;
      unsigned u0 = *(const unsigned*)(&srow[p]);
      unsigned u1 = *(const unsigned*)(&srow[p + 14]);
      float a = __uint_as_float(u0 << 16);
      float b = __uint_as_float(u0 & 0xffff0000u);
      float c = __uint_as_float(u1 << 16);
      float d = __uint_as_float(u1 & 0xffff0000u);
      float mx = fmaxf(fmaxf(a, b), fmaxf(c, d));
      float val = fmaxf(mx + bo, 0.f);
      fb[img][o * 49 + y7 * 7 + x7] =
          (u8)(__builtin_amdgcn_cvt_pk_fp8_f32(val, 0.f, 0, false) & 0xff);
      fsq += val * val;
    }
  }
  red[tid] = fsq;
  __syncthreads();
  for (int s = 64; s > 0; s >>= 1) {
    if ((tid & 127) < s) red[tid] += red[tid + s];
    __syncthreads();
  }
  if ((tid & 127) == 0) ef[bx * 2 + img] = __expf(-GAMMA * red[tid]);

  if (tid < 112) {
    int im = tid >= 56, j = tid - im * 56;
    uint4 v;
    if (j < 49) v = ((const uint4*)fb[im])[j];
    else { v.x = 0; v.y = 0; v.z = 0; v.w = 0; }
    int n = bx * 2 + im;
    int nt = n >> 7, nr = n & 127;
    int kk = j >> 3, u = j & 7, q = u >> 1, h = u & 1;
    int qs = q ^ ((nr >> 1) & 3);
    *(uint4*)(feats_t + (size_t)nt * TILE_BYTES + kk * 16384 + h * 8192 +
              nr * 64 + qs * 16) = v;
  }
}

__global__ __launch_bounds__(256, 4) void rbf_gemm_kernel(
    const u8* __restrict__ feats_t, const u8* __restrict__ sup_t,
    const float* __restrict__ beta, float* __restrict__ partial) {
  int tid = threadIdx.x;
  int wave = tid >> 6, lane = tid & 63;
  int bx = blockIdx.x;
  int chunk = bx & 63, nb = bx >> 6;
  int wn = wave >> 1, wm = wave & 1;
  int col = lane & 15, quad = lane >> 4;
  int slot = quad ^ ((col >> 1) & 3);

  const u8* abase = feats_t + (size_t)nb * TILE_BYTES +
                    (wn * 64 + col) * 64 + slot * 16;
  const u8* bbase = sup_t + (size_t)chunk * TILE_BYTES +
                    (wm * 64 + col) * 64 + slot * 16;

  f32x4 acc[4][4];
#pragma unroll
  for (int i = 0; i < 4; i++)
#pragma unroll
    for (int j = 0; j < 4; j++) acc[i][j] = (f32x4){0, 0, 0, 0};

#define LDFRAG(p)                                                      \
  ({                                                                   \
    int4 lo_ = *(const int4*)(p);                                      \
    int4 hi_ = *(const int4*)((p) + 8192);                             \
    (v8i){lo_.x, lo_.y, lo_.z, lo_.w, hi_.x, hi_.y, hi_.z, hi_.w};     \
  })
#define MFMA(a, b, c)                                                  \
  __builtin_amdgcn_mfma_scale_f32_16x16x128_f8f6f4(                    \
      (a), (b), (c), 0, 0, 0, 0x7f7f7f7f, 0, 0x7f7f7f7f)

#pragma unroll 1
  for (int kk = 0; kk < 7; ++kk) {
    const u8* ak = abase + kk * 16384;
    const u8* bk = bbase + kk * 16384;
    v8i bv0 = LDFRAG(bk);
    v8i bv1 = LDFRAG(bk + 1024);
    v8i bv2 = LDFRAG(bk + 2048);
    v8i bv3 = LDFRAG(bk + 3072);
    v8i a0 = LDFRAG(ak);
    v8i a1 = LDFRAG(ak + 1024);
    acc[0][0] = MFMA(a0, bv0, acc[0][0]);
    acc[0][1] = MFMA(a0, bv1, acc[0][1]);
    acc[0][2] = MFMA(a0, bv2, acc[0][2]);
    acc[0][3] = MFMA(a0, bv3, acc[0][3]);
    a0 = LDFRAG(ak + 2048);
    acc[1][0] = MFMA(a1, bv0, acc[1][0]);
    acc[1][1] = MFMA(a1, bv1, acc[1][1]);
    acc[1][2] = MFMA(a1, bv2, acc[1][2]);
    acc[1][3] = MFMA(a1, bv3, acc[1][3]);
    a1 = LDFRAG(ak + 3072);
    acc[2][0] = MFMA(a0, bv0, acc[2][0]);
    acc[2][1] = MFMA(a0, bv1, acc[2][1]);
    acc[2][2] = MFMA(a0, bv2, acc[2][2]);
    acc[2][3] = MFMA(a0, bv3, acc[2][3]);
    acc[3][0] = MFMA(a1, bv0, acc[3][0]);
    acc[3][1] = MFMA(a1, bv1, acc[3][1]);
    acc[3][2] = MFMA(a1, bv2, acc[3][2]);
    acc[3][3] = MFMA(a1, bv3, acc[3][3]);
  }
#undef LDFRAG
#undef MFMA

#pragma unroll
  for (int i = 0; i < 4; i++)
#pragma unroll
    for (int j = 0; j < 4; j++) {
      acc[i][j].x = __expf(2.f * GAMMA * acc[i][j].x);
      acc[i][j].y = __expf(2.f * GAMMA * acc[i][j].y);
      acc[i][j].z = __expf(2.f * GAMMA * acc[i][j].z);
      acc[i][j].w = __expf(2.f * GAMMA * acc[i][j].w);
    }
  int n0 = nb * 128, m0 = chunk * 128;
#pragma unroll
  for (int c = 0; c < 4; ++c) {
    float bl[4];
#pragma unroll
    for (int j = 0; j < 4; j++)
      bl[j] = beta[(m0 + wm * 64 + j * 16 + col) * 4 + c];
#pragma unroll
    for (int i = 0; i < 4; i++) {
      f32x4 s = acc[i][0] * bl[0] + acc[i][1] * bl[1] + acc[i][2] * bl[2] +
                acc[i][3] * bl[3];
#pragma unroll
      for (int st = 1; st < 16; st <<= 1) {
        s.x += __shfl_xor(s.x, st, 16);
        s.y += __shfl_xor(s.y, st, 16);
        s.z += __shfl_xor(s.z, st, 16);
        s.w += __shfl_xor(s.w, st, 16);
      }
      if (col == c) {
        int n = n0 + wn * 64 + i * 16 + quad * 4;
        float* pp = partial + (((size_t)chunk * 2 + wm) * 4096 + n) * 4 + c;
        pp[0] = s.x; pp[4] = s.y; pp[8] = s.z; pp[12] = s.w;
      }
    }
  }
}

__global__ __launch_bounds__(256) void reduce_kernel(
    const float* __restrict__ partial, const float* __restrict__ ef,
    float* __restrict__ out) {
  __shared__ float4 sred[16][16];
  int nl = threadIdx.x & 15, sg = threadIdx.x >> 4;
  int n = blockIdx.x * 16 + nl;
  const float4* p = (const float4*)partial;
  float sx = 0, sy = 0, sz = 0, sw = 0;
#pragma unroll
  for (int ch = sg * 8; ch < sg * 8 + 8; ch++) {
    float4 v = p[(size_t)ch * 4096 + n];
    sx += v.x; sy += v.y; sz += v.z; sw += v.w;
  }
  sred[sg][nl] = (float4){sx, sy, sz, sw};
  __syncthreads();
  for (int st = 8; st > 0; st >>= 1) {
    if (sg < st) {
      float4 a = sred[sg][nl], b = sred[sg + st][nl];
      sred[sg][nl] = (float4){a.x + b.x, a.y + b.y, a.z + b.z, a.w + b.w};
    }
    __syncthreads();
  }
  if (sg == 0) {
    float e = ef[n];
    float4 a = sred[0][nl];
    ((float4*)out)[n] = (float4){e * a.x, e * a.y, e * a.z, e * a.w};
  }
}

// ---------------------------------------------------------------------------
extern "C" void kernel_launch(void* const* d_in, const int* in_sizes, int n_in,
                              void* d_out, int out_size, void* d_ws,
                              size_t ws_size, hipStream_t stream) {
  const float* x = (const float*)d_in[0];
  const float* w1 = (const float*)d_in[1];
  const float* b1 = (const float*)d_in[2];
  const float* w2 = (const float*)d_in[3];
  const float* b2 = (const float*)d_in[4];
  const float* support = (const float*)d_in[5];
  const float* alpha = (const float*)d_in[6];
  float* out = (float*)d_out;

  u8* ws = (u8*)d_ws;
  u8* sup_t = ws;                                 // 64 tiles  = 7,340,032 B
  u8* feats_t = ws + 7340032;                     // 32 tiles  = 3,670,016 B
  float* beta = (float*)(ws + 11010048);          // 8192*4*4  =   131,072 B
  float* ef = (float*)(ws + 11141120);            // 4096*4    =    16,384 B
  float* partial = (float*)(ws + 11157504);       // 128*4096*4*4 = 8,388,608 B

  // grid = co-resident capacity (multiple of 64 preserves chunk->XCD map
  // and per-block B-chunk reuse across gemm iterations)
  static int coop_grid = 0;
  if (coop_grid == 0) {
    int per_cu = 0;
    if (hipOccupancyMaxActiveBlocksPerMultiprocessor(
            &per_cu, (const void*)fused_kernel, 256, 0) != hipSuccess ||
        per_cu <= 0)
      per_cu = 2;
    if (per_cu > 4) per_cu = 4;
    coop_grid = per_cu * 256;
    if (coop_grid > 1024) coop_grid = 1024;
    if (coop_grid < 256) coop_grid = 256;
  }

  void* kargs[] = {(void*)&x,       (void*)&w1,      (void*)&b1,
                   (void*)&w2,      (void*)&b2,      (void*)&support,
                   (void*)&alpha,   (void*)&feats_t, (void*)&sup_t,
                   (void*)&beta,    (void*)&ef,      (void*)&partial,
                   (void*)&out};
  hipError_t err = hipLaunchCooperativeKernel(
      (const void*)fused_kernel, dim3(coop_grid), dim3(256), kargs, 0, stream);
  if (err != hipSuccess) {
    (void)hipGetLastError();  // clear
    conv_prep_kernel<<<4096, 256, 0, stream>>>(x, w1, b1, w2, b2, support,
                                               alpha, feats_t, sup_t, beta,
                                               ef);
    rbf_gemm_kernel<<<2048, 256, 0, stream>>>(feats_t, sup_t, beta, partial);
    reduce_kernel<<<256, 256, 0, stream>>>(partial, ef, out);
  }
}

// Round 7
// 267.411 us; speedup vs baseline: 1.6936x; 1.4637x over previous
//
#include <hip/hip_runtime.h>
#include <hip/hip_bf16.h>
#include <cstdint>

#define GAMMA 0.001f
// K padded 784 -> 896 = 7*128. Swizzled fp8 tile layout per 128-row tile
// (R8/R9-proven): addr = tile*114688 + kk*16384 + h*8192 + row*64
//                        + (q ^ ((row>>1)&3))*16
// where source byte k = kk*128 + q*32 + h*16 + [0..15].
#define TILE_BYTES 114688

typedef __attribute__((ext_vector_type(4))) float f32x4;
typedef __attribute__((ext_vector_type(8))) int v8i;
typedef __attribute__((ext_vector_type(8))) short bh8;  // 8 bf16
typedef unsigned char u8;

__device__ inline unsigned pack4_fp8(float4 f) {
  unsigned p = __builtin_amdgcn_cvt_pk_fp8_f32(f.x, f.y, 0, false);
  p = __builtin_amdgcn_cvt_pk_fp8_f32(f.z, f.w, p, true);
  return p;
}

__device__ inline ushort bf16u(float v) {
  __hip_bfloat16 h = __float2bfloat16(v);
  return *(ushort*)&h;
}

// ---------------------------------------------------------------------------
// R20: back to SEPARATE kernels (fusion killed twice by joint regalloc:
// R5 (256,4) spilled 13MB, R6 (256,3) still spilled + VGPR=72 + 463us).
// But R4 vs R5/R6 bench-vs-profile deltas show ~20-30us FIXED COST PER
// LAUNCH in the timed region (total - sum(kernels) ~ 50-75us, constant
// across R0-R4). So: cut one launch WITHOUT joint compilation — fold the
// final reduce into the gemm kernel via last-block-per-nb ticketing
// (threadfence + device-scope atomicAdd, the guide's sanctioned cross-XCD
// pattern; no spinning -> no deadlock; separate kernels keep their own
// proven register allocations).
// Kernel 1 (conv_prep): byte-identical to R4 + zeroes the 32 tickets.
// Kernel 2 (gemm): R4 body + tail: 64th arrival per nb reduces 128 slots
// x 128 rows (256KB, ~2-3us, 32 reducers overlap other groups' compute).
// ---------------------------------------------------------------------------
__global__ __launch_bounds__(256, 4) void conv_prep_kernel(
    const float* __restrict__ x, const float* __restrict__ w1,
    const float* __restrict__ b1, const float* __restrict__ w2,
    const float* __restrict__ b2, const float* __restrict__ support,
    const float* __restrict__ alpha, u8* __restrict__ feats_t,
    u8* __restrict__ sup_t, float* __restrict__ beta, float* __restrict__ ef,
    unsigned* __restrict__ counters) {
  int tid = threadIdx.x;
  int bx = blockIdx.x;

  if (bx == 0 && tid < 32) counters[tid] = 0;  // tickets for gemm tail

  if (bx >= 2048) {  // ---- support prep: wave per row ----
    int lane = tid & 63, wave = tid >> 6;
    int m = (bx - 2048) * 4 + wave;
    const float* row = support + (size_t)m * 784;
    int mt = m >> 7, mr = m & 127;
    u8* tb = sup_t + (size_t)mt * TILE_BYTES;
    float ss = 0.f;
    if (lane < 56) {  // 16B unit j covers source bytes 16j..16j+15
      uint4 w;
      if (lane < 49) {
        float4 f0 = ((const float4*)row)[lane * 4 + 0];
        float4 f1 = ((const float4*)row)[lane * 4 + 1];
        float4 f2 = ((const float4*)row)[lane * 4 + 2];
        float4 f3 = ((const float4*)row)[lane * 4 + 3];
        ss = f0.x * f0.x + f0.y * f0.y + f0.z * f0.z + f0.w * f0.w +
             f1.x * f1.x + f1.y * f1.y + f1.z * f1.z + f1.w * f1.w +
             f2.x * f2.x + f2.y * f2.y + f2.z * f2.z + f2.w * f2.w +
             f3.x * f3.x + f3.y * f3.y + f3.z * f3.z + f3.w * f3.w;
        w.x = pack4_fp8(f0); w.y = pack4_fp8(f1);
        w.z = pack4_fp8(f2); w.w = pack4_fp8(f3);
      } else {
        w.x = 0; w.y = 0; w.z = 0; w.w = 0;
      }
      int kk = lane >> 3, u = lane & 7, q = u >> 1, h = u & 1;
      int qs = q ^ ((mr >> 1) & 3);
      *(uint4*)(tb + kk * 16384 + h * 8192 + mr * 64 + qs * 16) = w;
    }
#pragma unroll
    for (int s = 1; s < 64; s <<= 1) ss += __shfl_xor(ss, s, 64);
    if (lane == 0) {
      float es = __expf(-GAMMA * ss);
      float4 a = ((const float4*)alpha)[m];
      float4 b;
      b.x = es * a.x; b.y = es * a.y; b.z = es * a.z; b.w = es * a.w;
      ((float4*)beta)[m] = b;
    }
    return;
  }

  // ---- conv pair ----
  __shared__ float xp[2][900];                 // 30x30 zero-padded input
  __shared__ alignas(16) ushort a1h[2][2048];  // HWC bf16: (row*16+col)*8+ic
  __shared__ float w1s[72], b1s[8], b2s[16];
  __shared__ float w2s[1152];                  // raw w2 [oc][ic][9]
  __shared__ alignas(8) ushort sc[2][16][212]; // conv2 out bf16 [oc][pos]
  __shared__ alignas(16) u8 fb[2][784];
  __shared__ float red[256];

  int lane = tid & 63, wave = tid >> 6;

  for (int t = tid; t < 1800; t += 256) ((float*)xp)[t] = 0.f;
  for (int t = tid; t < 1024; t += 256) ((uint4*)a1h)[t] = (uint4){0, 0, 0, 0};
  if (tid < 72) w1s[tid] = w1[tid];
  if (tid < 8) b1s[tid] = b1[tid];
  if (tid < 16) b2s[tid] = b2[tid];
  for (int t = tid; t < 1152; t += 256) w2s[t] = w2[t];
  __syncthreads();

  // build per-lane B-frags (weights): oc=lane&15, quad covers k=quad*8+j,
  // k=(tap=g*4+quad, ic=j); taps>=9 are zero.
  int oc = lane & 15, quad = lane >> 4;
  bh8 wf[3];
#pragma unroll
  for (int g = 0; g < 3; g++) {
    int tap = g * 4 + quad;
#pragma unroll
    for (int j = 0; j < 8; j++) {
      float v = (tap < 9) ? w2s[oc * 72 + j * 9 + tap] : 0.f;
      wf[g][j] = (short)bf16u(v);
    }
  }

  for (int t = tid; t < 392; t += 256) {
    int img = t >= 196, j = t - img * 196;
    float4 v = ((const float4*)(x + (size_t)(bx * 2 + img) * 784))[j];
    int r = j / 7, c = (j % 7) * 4;
    float* p = &xp[img][(r + 1) * 30 + (c + 1)];
    p[0] = v.x; p[1] = v.y; p[2] = v.z; p[3] = v.w;
  }
  __syncthreads();

  // stage 1: conv1(3x3,SAME)+bias+relu+maxpool2 -> a1h (HWC bf16) interiors
  for (int idx = tid; idx < 3136; idx += 256) {
    int img = idx >= 1568;
    int rem = idx - img * 1568;
    int c = rem / 196, r2 = rem % 196;
    int ph = r2 / 14, pw = r2 % 14;
    const float* w = &w1s[c * 9];
    const float* xb = &xp[img][(2 * ph) * 30 + (2 * pw)];
    float t[4][4];
#pragma unroll
    for (int a = 0; a < 4; a++) {
      float2 u0 = *(const float2*)(xb + a * 30);
      float2 u1 = *(const float2*)(xb + a * 30 + 2);
      t[a][0] = u0.x; t[a][1] = u0.y; t[a][2] = u1.x; t[a][3] = u1.y;
    }
    float s00 = 0, s01 = 0, s10 = 0, s11 = 0;
#pragma unroll
    for (int dy = 0; dy < 3; dy++)
#pragma unroll
      for (int dx = 0; dx < 3; dx++) {
        float wv = w[dy * 3 + dx];
        s00 += t[dy][dx] * wv;     s01 += t[dy][dx + 1] * wv;
        s10 += t[dy + 1][dx] * wv; s11 += t[dy + 1][dx + 1] * wv;
      }
    float mx = fmaxf(fmaxf(s00, s01), fmaxf(s10, s11));
    float val = fmaxf(mx + b1s[c], 0.f);
    a1h[img][((ph + 1) * 16 + (pw + 1)) * 8 + c] = bf16u(val);
  }
  __syncthreads();

  // stage 2 (MFMA): waves 0,1 -> img0 tiles 0-6/7-12; waves 2,3 -> img1.
  {
    int img2 = wave >> 1, half = wave & 1;
    int Tstart = half * 7, Tcnt = half ? 6 : 7;
    const ushort* abase = a1h[img2];
    int mrow = lane & 15;  // A-row (pos-in-tile) during reads
    for (int t = 0; t < Tcnt; ++t) {
      int T = Tstart + t;
      int p = T * 16 + mrow;
      int pc = p > 195 ? 195 : p;
      int y = pc / 14, xq = pc - y * 14;
      int cell = y * 16 + xq;
      f32x4 acc = (f32x4){0, 0, 0, 0};
#pragma unroll
      for (int g = 0; g < 3; g++) {
        int tap = g * 4 + quad;
        const ushort* ap;
        if (g == 2 && quad > 0) {
          ap = abase;  // border cell (0,0): guaranteed zeros
        } else {
          int dy = tap / 3, dx = tap - dy * 3;
          ap = abase + (cell + dy * 16 + dx) * 8;
        }
        bh8 af = *(const bh8*)ap;
        acc = __builtin_amdgcn_mfma_f32_16x16x32_bf16(af, wf[g], acc, 0, 0, 0);
      }
      // D: col=lane&15=oc, row=quad*4+r = pos-in-tile
      int pos0 = T * 16 + quad * 4;
      ushort4 s4;
      s4.x = bf16u(acc.x); s4.y = bf16u(acc.y);
      s4.z = bf16u(acc.z); s4.w = bf16u(acc.w);
      *(ushort4*)(&sc[img2][oc][pos0]) = s4;
    }
  }
  __syncthreads();

  // pooling + bias + relu + fp8 + fsq from sc
  int img = tid >> 7, r = tid & 127;
  float fsq = 0.f;
  if (r < 112) {
    int o = r & 15, y7 = r >> 4;
    const ushort* srow = sc[img][o];
    float bo = b2s[o];
#pragma unroll
    for (int x7 = 0; x7 < 7; x7++) {
      int p = 28 * y7 + 2 * x7;
      unsigned u0 = *(const unsigned*)(&srow[p]);
      unsigned u1 = *(const unsigned*)(&srow[p + 14]);
      float a = __uint_as_float(u0 << 16);
      float b = __uint_as_float(u0 & 0xffff0000u);
      float c = __uint_as_float(u1 << 16);
      float d = __uint_as_float(u1 & 0xffff0000u);
      float mx = fmaxf(fmaxf(a, b), fmaxf(c, d));
      float val = fmaxf(mx + bo, 0.f);
      fb[img][o * 49 + y7 * 7 + x7] =
          (u8)(__builtin_amdgcn_cvt_pk_fp8_f32(val, 0.f, 0, false) & 0xff);
      fsq += val * val;
    }
  }
  red[tid] = fsq;
  __syncthreads();
  for (int s = 64; s > 0; s >>= 1) {
    if ((tid & 127) < s) red[tid] += red[tid + s];
    __syncthreads();
  }
  if ((tid & 127) == 0) ef[bx * 2 + img] = __expf(-GAMMA * red[tid]);

  // store feats: 2 imgs x 56 16B-units into swizzled tile layout
  if (tid < 112) {
    int im = tid >= 56, j = tid - im * 56;
    uint4 v;
    if (j < 49) v = ((const uint4*)fb[im])[j];
    else { v.x = 0; v.y = 0; v.z = 0; v.w = 0; }
    int n = bx * 2 + im;
    int nt = n >> 7, nr = n & 127;
    int kk = j >> 3, u = j & 7, q = u >> 1, h = u & 1;
    int qs = q ^ ((nr >> 1) & 3);
    *(uint4*)(feats_t + (size_t)nt * TILE_BYTES + kk * 16384 + h * 8192 +
              nr * 64 + qs * 16) = v;
  }
}

// ---------------------------------------------------------------------------
// Kernel 2: fused RBF GEMM + last-block final reduce. R4-proven body
// (no-LDS K-loop, A-frag ping-pong, (256,4), VGPR=64, 53us) + tail:
// per-nb ticket; 64th arriving chunk-block reduces its 128 rows over all
// 128 partial slots and writes out = ef * sum. Cross-XCD visibility:
// __syncthreads drains vmcnt (stores in own XCD L2) -> tid0 __threadfence
// (agent-scope release, L2 writeback) -> device-scope atomicAdd; reader
// fences after winning the ticket (guide §6 G16 sanctioned pattern).
// SPILL TRIPWIRE: WRITE_SIZE ~8.5MB (R12 spill showed 307MB).
// ---------------------------------------------------------------------------
__global__ __launch_bounds__(256, 4) void rbf_gemm_kernel(
    const u8* __restrict__ feats_t, const u8* __restrict__ sup_t,
    const float* __restrict__ beta, float* __restrict__ partial,
    const float* __restrict__ ef, float* __restrict__ out,
    unsigned* __restrict__ counters) {
  __shared__ float4 sred[128];
  __shared__ unsigned sticket;
  int tid = threadIdx.x;
  int wave = tid >> 6, lane = tid & 63;
  int bx = blockIdx.x;
  int chunk = bx & 63, nb = bx >> 6;
  int wn = wave >> 1, wm = wave & 1;
  int col = lane & 15, quad = lane >> 4;
  int slot = quad ^ ((col >> 1) & 3);

  // per-lane fragment base addresses (lo 16B; hi at +8192).
  // frag i/j adds i*1024 (=16 rows * 64B); K-iter kk adds kk*16384.
  const u8* abase = feats_t + (size_t)nb * TILE_BYTES +
                    (wn * 64 + col) * 64 + slot * 16;
  const u8* bbase = sup_t + (size_t)chunk * TILE_BYTES +
                    (wm * 64 + col) * 64 + slot * 16;

  f32x4 acc[4][4];
#pragma unroll
  for (int i = 0; i < 4; i++)
#pragma unroll
    for (int j = 0; j < 4; j++) acc[i][j] = (f32x4){0, 0, 0, 0};

#define LDFRAG(p)                                                      \
  ({                                                                   \
    int4 lo_ = *(const int4*)(p);                                      \
    int4 hi_ = *(const int4*)((p) + 8192);                             \
    (v8i){lo_.x, lo_.y, lo_.z, lo_.w, hi_.x, hi_.y, hi_.z, hi_.w};     \
  })
#define MFMA(a, b, c)                                                  \
  __builtin_amdgcn_mfma_scale_f32_16x16x128_f8f6f4(                    \
      (a), (b), (c), 0, 0, 0, 0x7f7f7f7f, 0, 0x7f7f7f7f)

#pragma unroll 1
  for (int kk = 0; kk < 7; ++kk) {
    const u8* ak = abase + kk * 16384;
    const u8* bk = bbase + kk * 16384;
    // all 4 B-frags resident; A-frags ping-pong (a0,a1) to cap live regs.
    v8i bv0 = LDFRAG(bk);
    v8i bv1 = LDFRAG(bk + 1024);
    v8i bv2 = LDFRAG(bk + 2048);
    v8i bv3 = LDFRAG(bk + 3072);
    v8i a0 = LDFRAG(ak);
    v8i a1 = LDFRAG(ak + 1024);
    acc[0][0] = MFMA(a0, bv0, acc[0][0]);
    acc[0][1] = MFMA(a0, bv1, acc[0][1]);
    acc[0][2] = MFMA(a0, bv2, acc[0][2]);
    acc[0][3] = MFMA(a0, bv3, acc[0][3]);
    a0 = LDFRAG(ak + 2048);
    acc[1][0] = MFMA(a1, bv0, acc[1][0]);
    acc[1][1] = MFMA(a1, bv1, acc[1][1]);
    acc[1][2] = MFMA(a1, bv2, acc[1][2]);
    acc[1][3] = MFMA(a1, bv3, acc[1][3]);
    a1 = LDFRAG(ak + 3072);
    acc[2][0] = MFMA(a0, bv0, acc[2][0]);
    acc[2][1] = MFMA(a0, bv1, acc[2][1]);
    acc[2][2] = MFMA(a0, bv2, acc[2][2]);
    acc[2][3] = MFMA(a0, bv3, acc[2][3]);
    acc[3][0] = MFMA(a1, bv0, acc[3][0]);
    acc[3][1] = MFMA(a1, bv1, acc[3][1]);
    acc[3][2] = MFMA(a1, bv2, acc[3][2]);
    acc[3][3] = MFMA(a1, bv3, acc[3][3]);
  }
#undef LDFRAG
#undef MFMA

  // epilogue: Kv = exp(2*gamma*G) in place (C/D: col=m-idx, quad*4+rr=n-idx)
#pragma unroll
  for (int i = 0; i < 4; i++)
#pragma unroll
    for (int j = 0; j < 4; j++) {
      acc[i][j].x = __expf(2.f * GAMMA * acc[i][j].x);
      acc[i][j].y = __expf(2.f * GAMMA * acc[i][j].y);
      acc[i][j].z = __expf(2.f * GAMMA * acc[i][j].z);
      acc[i][j].w = __expf(2.f * GAMMA * acc[i][j].w);
    }
  int n0 = nb * 128, m0 = chunk * 128;
#pragma unroll
  for (int c = 0; c < 4; ++c) {
    float bl[4];
#pragma unroll
    for (int j = 0; j < 4; j++)
      bl[j] = beta[(m0 + wm * 64 + j * 16 + col) * 4 + c];
#pragma unroll
    for (int i = 0; i < 4; i++) {
      f32x4 s = acc[i][0] * bl[0] + acc[i][1] * bl[1] + acc[i][2] * bl[2] +
                acc[i][3] * bl[3];
#pragma unroll
      for (int st = 1; st < 16; st <<= 1) {
        s.x += __shfl_xor(s.x, st, 16);
        s.y += __shfl_xor(s.y, st, 16);
        s.z += __shfl_xor(s.z, st, 16);
        s.w += __shfl_xor(s.w, st, 16);
      }
      if (col == c) {
        int n = n0 + wn * 64 + i * 16 + quad * 4;
        float* pp = partial + (((size_t)chunk * 2 + wm) * 4096 + n) * 4 + c;
        pp[0] = s.x; pp[4] = s.y; pp[8] = s.z; pp[12] = s.w;
      }
    }
  }

  // ---- tail: last-arriving block of this nb reduces and writes out ----
  __syncthreads();  // all partial stores issued; vmcnt(0) drained at barrier
  if (tid == 0) {
    __threadfence();  // agent-scope release: our XCD L2 -> device-visible
    sticket = atomicAdd(&counters[nb], 1u);
  }
  __syncthreads();
  if (sticket == 63u) {
    __threadfence();  // acquire side
    int nl = tid & 127, sg = tid >> 7;
    int n = n0 + nl;
    const float4* p4 = (const float4*)partial;
    float sx = 0.f, sy = 0.f, sz = 0.f, sw = 0.f;
    for (int ch = sg * 64; ch < sg * 64 + 64; ch++) {
      float4 v = p4[(size_t)ch * 4096 + n];
      sx += v.x; sy += v.y; sz += v.z; sw += v.w;
    }
    if (sg == 1) sred[nl] = (float4){sx, sy, sz, sw};
    __syncthreads();
    if (sg == 0) {
      float4 b = sred[nl];
      float e = ef[n];
      ((float4*)out)[n] =
          (float4){e * (sx + b.x), e * (sy + b.y), e * (sz + b.z),
                   e * (sw + b.w)};
    }
  }
}

// ---------------------------------------------------------------------------
extern "C" void kernel_launch(void* const* d_in, const int* in_sizes, int n_in,
                              void* d_out, int out_size, void* d_ws,
                              size_t ws_size, hipStream_t stream) {
  const float* x = (const float*)d_in[0];
  const float* w1 = (const float*)d_in[1];
  const float* b1 = (const float*)d_in[2];
  const float* w2 = (const float*)d_in[3];
  const float* b2 = (const float*)d_in[4];
  const float* support = (const float*)d_in[5];
  const float* alpha = (const float*)d_in[6];
  float* out = (float*)d_out;

  u8* ws = (u8*)d_ws;
  u8* sup_t = ws;                                 // 64 tiles  = 7,340,032 B
  u8* feats_t = ws + 7340032;                     // 32 tiles  = 3,670,016 B
  float* beta = (float*)(ws + 11010048);          // 8192*4*4  =   131,072 B
  float* ef = (float*)(ws + 11141120);            // 4096*4    =    16,384 B
  float* partial = (float*)(ws + 11157504);       // 128*4096*4*4 = 8,388,608 B
  unsigned* counters = (unsigned*)(ws + 19546112);  // 32*4 = 128 B

  conv_prep_kernel<<<4096, 256, 0, stream>>>(x, w1, b1, w2, b2, support, alpha,
                                             feats_t, sup_t, beta, ef,
                                             counters);
  rbf_gemm_kernel<<<2048, 256, 0, stream>>>(feats_t, sup_t, beta, partial, ef,
                                            out, counters);
}